// Round 7
// baseline (2673.910 us; speedup 1.0000x reference)
//
#include <hip/hip_runtime.h>
#include <stdint.h>

#define SEQ 8192
#define B   40
#define EMBD 64
#define HID 40
#define VOCAB 201
#define LOG2E 1.4426950408889634f

typedef _Float16 v2h __attribute__((ext_vector_type(2)));

__device__ __forceinline__ float fexp2(float x) { float r; asm("v_exp_f32 %0, %1" : "=v"(r) : "v"(x)); return r; }
__device__ __forceinline__ float frcp (float x) { float r; asm("v_rcp_f32 %0, %1" : "=v"(r) : "v"(x)); return r; }
__device__ __forceinline__ float sigm (float x) { return frcp(1.f + fexp2(-LOG2E * x)); }
__device__ __forceinline__ float tanh_(float x) { return fmaf(2.f, frcp(1.f + fexp2(-2.f * LOG2E * x)), -1.f); }
__device__ __forceinline__ v2h rdpair(v2h v, int k) {
    int r = __builtin_amdgcn_readlane(__builtin_bit_cast(int, v), k);
    return __builtin_bit_cast(v2h, r);
}
__device__ __forceinline__ v2h pkrtz(float lo, float hi) {
    return __builtin_bit_cast(v2h, __builtin_amdgcn_cvt_pkrtz(lo, hi));
}

// ---------------- kernel A: packed-f16 gate table: tabh[v*HID+e] = {pk(i,f), pk(g,o)} ----------------
__global__ void setup_kernel(const float* __restrict__ emb, const float* __restrict__ Wih,
                             const float* __restrict__ bih, const float* __restrict__ bhh,
                             uint2* __restrict__ tabh) {
    const int v = blockIdx.x;          // 0..200
    const int e = threadIdx.x;         // 0..63, active < 40
    if (e >= HID) return;
    const float* er = emb + v * EMBD;
    float acc[4];
#pragma unroll
    for (int g = 0; g < 4; ++g) {
        const int j = g * HID + e;
        const float* wr = Wih + j * EMBD;
        float a = bih[j] + bhh[j];
#pragma unroll 8
        for (int k = 0; k < EMBD; ++k) a = fmaf(er[k], wr[k], a);
        acc[g] = a;
    }
    v2h p01 = pkrtz(acc[0], acc[1]);
    v2h p23 = pkrtz(acc[2], acc[3]);
    tabh[v * HID + e] = make_uint2(__builtin_bit_cast(uint32_t, p01),
                                   __builtin_bit_cast(uint32_t, p23));
}

// ---------------- kernel B: encoder — 1 wave/chain; table in LDS; zero global loads in loop ----------------
__global__ __attribute__((amdgpu_flat_work_group_size(64, 64), amdgpu_waves_per_eu(1, 1)))
void enc_kernel(const int* __restrict__ src,
                const float* __restrict__ Whh,
                const uint2* __restrict__ tabh,
                float* __restrict__ est) {
    const int b    = blockIdx.x;
    const int lane = threadIdx.x;
    const int e    = (lane < HID) ? lane : 0;   // clamp idle lanes

    __shared__ uint2 stab[VOCAB * HID];          // 64,320 B packed-f16 gate table

    // stage table to LDS (one-time): 4020 uint4
    {
        const uint4* g4 = reinterpret_cast<const uint4*>(tabh);
        uint4* l4 = reinterpret_cast<uint4*>(stab);
        for (int i = lane; i < (VOCAB * HID) / 2; i += 64) l4[i] = g4[i];
    }

    // weights as f16 pairs -- 80 VGPRs total
    v2h wi[20], wf[20], wg[20], wo[20];
#pragma unroll
    for (int r = 0; r < 10; ++r) {
        float4 ai = *reinterpret_cast<const float4*>(&Whh[(0 * HID + e) * HID + 4 * r]);
        float4 af = *reinterpret_cast<const float4*>(&Whh[(1 * HID + e) * HID + 4 * r]);
        float4 ag = *reinterpret_cast<const float4*>(&Whh[(2 * HID + e) * HID + 4 * r]);
        float4 ao = *reinterpret_cast<const float4*>(&Whh[(3 * HID + e) * HID + 4 * r]);
        wi[2*r]   = (v2h){(_Float16)ai.x, (_Float16)ai.y};
        wi[2*r+1] = (v2h){(_Float16)ai.z, (_Float16)ai.w};
        wf[2*r]   = (v2h){(_Float16)af.x, (_Float16)af.y};
        wf[2*r+1] = (v2h){(_Float16)af.z, (_Float16)af.w};
        wg[2*r]   = (v2h){(_Float16)ag.x, (_Float16)ag.y};
        wg[2*r+1] = (v2h){(_Float16)ag.z, (_Float16)ag.w};
        wo[2*r]   = (v2h){(_Float16)ao.x, (_Float16)ao.y};
        wo[2*r+1] = (v2h){(_Float16)ao.z, (_Float16)ao.w};
    }

    float c = 0.f, h = 0.f;
    __syncthreads();   // table staged

    // index prefetch window: i2..i6 = idx(t+2..t+6) at loop entry
    int idx0 = src[0 * B + b], idx1 = src[1 * B + b];
    int i2 = src[2 * B + b], i3 = src[3 * B + b], i4 = src[4 * B + b],
        i5 = src[5 * B + b], i6 = src[6 * B + b];

    // x-part prefetch: xq0 = t, xq1 = t+1
    uint2 xq0 = stab[idx0 * HID + e];
    uint2 xq1 = stab[idx1 * HID + e];

    v2h hpk = (v2h){(_Float16)0.f, (_Float16)0.f};

#pragma unroll 4
    for (int t = 0; t < SEQ; ++t) {
        // LDS prefetch of x-part for t+2; global prefetch of idx(t+7)
        uint2 xq2 = stab[i2 * HID + e];
        int in7 = src[((t + 7) & (SEQ - 1)) * B + b];

        // unpack x-part (f16 -> f32)
        v2h p01 = __builtin_bit_cast(v2h, xq0.x);
        v2h p23 = __builtin_bit_cast(v2h, xq0.y);
        float ai0 = (float)p01.x, ai1 = 0.f;
        float af0 = (float)p01.y, af1 = 0.f;
        float ag0 = (float)p23.x, ag1 = 0.f;
        float ao0 = (float)p23.y, ao1 = 0.f;

#pragma unroll
        for (int m = 0; m < 20; m += 2) {
            v2h h0 = rdpair(hpk, 2 * m);
            v2h h1 = rdpair(hpk, 2 * m + 2);
            ai0 = __builtin_amdgcn_fdot2(wi[m],   h0, ai0, false);
            af0 = __builtin_amdgcn_fdot2(wf[m],   h0, af0, false);
            ag0 = __builtin_amdgcn_fdot2(wg[m],   h0, ag0, false);
            ao0 = __builtin_amdgcn_fdot2(wo[m],   h0, ao0, false);
            ai1 = __builtin_amdgcn_fdot2(wi[m+1], h1, ai1, false);
            af1 = __builtin_amdgcn_fdot2(wf[m+1], h1, af1, false);
            ag1 = __builtin_amdgcn_fdot2(wg[m+1], h1, ag1, false);
            ao1 = __builtin_amdgcn_fdot2(wo[m+1], h1, ao1, false);
        }
        float si = sigm(ai0 + ai1);
        float sf = sigm(af0 + af1);
        float tg = tanh_(ag0 + ag1);
        float so = sigm(ao0 + ao1);

        c = fmaf(sf, c, si * tg);
        h = so * tanh_(c);

        // repack h into f16 pairs (both lanes of a pair hold (h[2m],h[2m+1]))
        float hp = __shfl_xor(h, 1);
        float lo = (lane & 1) ? hp : h;
        float hi = (lane & 1) ? h : hp;
        hpk = pkrtz(lo, hi);

        // rotate prefetch windows
        xq0 = xq1; xq1 = xq2;
        i2 = i3; i3 = i4; i4 = i5; i5 = i6; i6 = in7;
    }

    if (lane < HID) {
        est[b * 80 + lane]       = h;
        est[b * 80 + HID + lane] = c;
    }
}

// ---------------- kernel C: decoder, 40 steps, 1 chain per block (3 waves, fp32) ----------------
__global__ __launch_bounds__(192, 1) void dec_kernel(const float* __restrict__ dinp,
                                                     const float* __restrict__ Wih,
                                                     const float* __restrict__ Whh,
                                                     const float* __restrict__ bih,
                                                     const float* __restrict__ bhh,
                                                     const float* __restrict__ est,
                                                     float* __restrict__ out) {
    const int b    = blockIdx.x;
    const int tid  = threadIdx.x;
    const int lane = tid & 63;
    const int w    = tid >> 6;
    const int tt   = lane >> 4;
    const int q    = lane & 15;
    const int e    = 16 * w + q;
    const bool valid = (e < HID);
    const bool own   = valid && (tt == 0);
    const int j    = tt * HID + (valid ? e : 0);

    __shared__ __align__(16) float hbuf[2][48];

    float4 wi4[10], wh4[10];
#pragma unroll
    for (int r = 0; r < 10; ++r) {
        float4 ti = *reinterpret_cast<const float4*>(&Wih[j * HID + 4 * r]);
        float4 th = *reinterpret_cast<const float4*>(&Whh[j * HID + 4 * r]);
        if (!valid) { ti = make_float4(0,0,0,0); th = make_float4(0,0,0,0); }
        wi4[r] = ti; wh4[r] = th;
    }
    const float bj = valid ? (bih[j] + bhh[j]) : 0.f;

    const float mcoef = (tt == 2) ? (-2.f * LOG2E) : (-LOG2E);
    const float vsc   = (tt == 2) ? 2.f : 1.f;
    const float voff  = (tt == 2) ? -1.f : 0.f;

    float4 xr4[10], hr4[10];
#pragma unroll
    for (int r = 0; r < 10; ++r) {
        xr4[r] = *reinterpret_cast<const float4*>(&dinp[b * HID + 4 * r]);
        hr4[r] = *reinterpret_cast<const float4*>(&est[b * 80 + 4 * r]);
    }
    float c = valid ? est[b * 80 + HID + e] : 0.f;

    for (int t = 0; t < B; ++t) {
        float a0 = bj, a1 = 0.f, a2 = 0.f, a3 = 0.f;
#pragma unroll
        for (int r = 0; r < 10; ++r) {
            a0 = fmaf(wi4[r].x, xr4[r].x, a0);
            a1 = fmaf(wi4[r].y, xr4[r].y, a1);
            a2 = fmaf(wi4[r].z, xr4[r].z, a2);
            a3 = fmaf(wi4[r].w, xr4[r].w, a3);
            a0 = fmaf(wh4[r].x, hr4[r].x, a0);
            a1 = fmaf(wh4[r].y, hr4[r].y, a1);
            a2 = fmaf(wh4[r].z, hr4[r].z, a2);
            a3 = fmaf(wh4[r].w, hr4[r].w, a3);
        }
        float xg = (a0 + a1) + (a2 + a3);

        float E   = fexp2(mcoef * xg);
        float v   = frcp(1.f + E);
        float act = fmaf(vsc, v, voff);

        float ig = __shfl(act, q);
        float fg = __shfl(act, q + 16);
        float gg = __shfl(act, q + 32);
        float og = __shfl(act, q + 48);

        c = fmaf(fg, c, ig * gg);
        float Ec = fexp2(-2.f * LOG2E * c);
        float th = fmaf(2.f, frcp(1.f + Ec), -1.f);
        float h  = og * th;

        if (own) out[(t * B + b) * HID + e] = h;

        if (own) hbuf[t & 1][e] = h;
        __syncthreads();
#pragma unroll
        for (int r = 0; r < 10; ++r) {
            hr4[r] = *reinterpret_cast<const float4*>(&hbuf[t & 1][4 * r]);
            xr4[r] = hr4[r];   // next input is current output
        }
    }
}

extern "C" void kernel_launch(void* const* d_in, const int* in_sizes, int n_in,
                              void* d_out, int out_size, void* d_ws, size_t ws_size,
                              hipStream_t stream) {
    const int*   src  = (const int*)  d_in[0];
    const float* dinp = (const float*)d_in[1];
    const float* emb  = (const float*)d_in[2];
    const float* eWih = (const float*)d_in[3];
    const float* eWhh = (const float*)d_in[4];
    const float* ebih = (const float*)d_in[5];
    const float* ebhh = (const float*)d_in[6];
    const float* dWih = (const float*)d_in[7];
    const float* dWhh = (const float*)d_in[8];
    const float* dbih = (const float*)d_in[9];
    const float* dbhh = (const float*)d_in[10];
    float* out = (float*)d_out;

    uint2* tabh = (uint2*)d_ws;                              // 201*40 uint2 (packed f16)
    float* est  = (float*)((char*)d_ws + VOCAB * HID * 8);   // 40*80 floats

    hipLaunchKernelGGL(setup_kernel, dim3(VOCAB), dim3(64), 0, stream, emb, eWih, ebih, ebhh, tabh);
    hipLaunchKernelGGL(enc_kernel,   dim3(B),     dim3(64), 0, stream, src, eWhh, tabh, est);
    hipLaunchKernelGGL(dec_kernel,   dim3(B),     dim3(192), 0, stream, dinp, dWih, dWhh, dbih, dbhh, est, out);
}

// Round 8
// 2558.027 us; speedup vs baseline: 1.0453x; 1.0453x over previous
//
#include <hip/hip_runtime.h>
#include <stdint.h>

#define SEQ 8192
#define B   40
#define EMBD 64
#define HID 40
#define VOCAB 201
#define LOG2E 1.4426950408889634f

typedef _Float16 v2h __attribute__((ext_vector_type(2)));

__device__ __forceinline__ float fexp2(float x) { float r; asm("v_exp_f32 %0, %1" : "=v"(r) : "v"(x)); return r; }
__device__ __forceinline__ float frcp (float x) { float r; asm("v_rcp_f32 %0, %1" : "=v"(r) : "v"(x)); return r; }
__device__ __forceinline__ v2h rdpair(v2h v, int k) {
    int r = __builtin_amdgcn_readlane(__builtin_bit_cast(int, v), k);
    return __builtin_bit_cast(v2h, r);
}
__device__ __forceinline__ v2h pkrtz(float lo, float hi) {
    return __builtin_bit_cast(v2h, __builtin_amdgcn_cvt_pkrtz(lo, hi));
}

// ---------------- kernel A: PRESCALED table: (i,f,o)*-log2e, g*-2log2e ----------------
__global__ void setup_kernel(const float* __restrict__ emb, const float* __restrict__ Wih,
                             const float* __restrict__ bih, const float* __restrict__ bhh,
                             float4* __restrict__ table4) {
    const int v = blockIdx.x;          // 0..200
    const int e = threadIdx.x;         // 0..63, active < 40
    if (e >= HID) return;
    const float* er = emb + v * EMBD;
    float acc[4];
#pragma unroll
    for (int g = 0; g < 4; ++g) {
        const int j = g * HID + e;
        const float* wr = Wih + j * EMBD;
        float a = bih[j] + bhh[j];
#pragma unroll 8
        for (int k = 0; k < EMBD; ++k) a = fmaf(er[k], wr[k], a);
        acc[g] = a;
    }
    table4[v * HID + e] = make_float4(-LOG2E * acc[0], -LOG2E * acc[1],
                                      -2.f * LOG2E * acc[2], -LOG2E * acc[3]);
}

// ---------------- kernel B: encoder — 1 wave/chain; no LDS; prescaled f16 weights ----------------
__global__ __attribute__((amdgpu_flat_work_group_size(64, 64), amdgpu_waves_per_eu(1, 1)))
void enc_kernel(const int* __restrict__ src,
                const float* __restrict__ Whh,
                const float4* __restrict__ tbl,
                float* __restrict__ est) {
    const int b    = blockIdx.x;
    const int lane = threadIdx.x;
    const int e    = (lane < HID) ? lane : 0;   // clamp idle lanes

    // weights as prescaled f16 pairs -- 80 VGPRs total
    v2h wi[20], wf[20], wg[20], wo[20];
#pragma unroll
    for (int r = 0; r < 10; ++r) {
        float4 ai = *reinterpret_cast<const float4*>(&Whh[(0 * HID + e) * HID + 4 * r]);
        float4 af = *reinterpret_cast<const float4*>(&Whh[(1 * HID + e) * HID + 4 * r]);
        float4 ag = *reinterpret_cast<const float4*>(&Whh[(2 * HID + e) * HID + 4 * r]);
        float4 ao = *reinterpret_cast<const float4*>(&Whh[(3 * HID + e) * HID + 4 * r]);
        const float sl = -LOG2E, sg = -2.f * LOG2E;
        wi[2*r]   = (v2h){(_Float16)(sl*ai.x), (_Float16)(sl*ai.y)};
        wi[2*r+1] = (v2h){(_Float16)(sl*ai.z), (_Float16)(sl*ai.w)};
        wf[2*r]   = (v2h){(_Float16)(sl*af.x), (_Float16)(sl*af.y)};
        wf[2*r+1] = (v2h){(_Float16)(sl*af.z), (_Float16)(sl*af.w)};
        wg[2*r]   = (v2h){(_Float16)(sg*ag.x), (_Float16)(sg*ag.y)};
        wg[2*r+1] = (v2h){(_Float16)(sg*ag.z), (_Float16)(sg*ag.w)};
        wo[2*r]   = (v2h){(_Float16)(sl*ao.x), (_Float16)(sl*ao.y)};
        wo[2*r+1] = (v2h){(_Float16)(sl*ao.z), (_Float16)(sl*ao.w)};
    }

    float c = 0.f, h = 0.f;
    v2h hpk = (v2h){(_Float16)0.f, (_Float16)0.f};

    // index window (wave-uniform -> scalar loads) and fp32 table prefetch (distance 3)
    int i3 = src[3 * B + b];
    float4 tq0 = tbl[src[0 * B + b] * HID + e];
    float4 tq1 = tbl[src[1 * B + b] * HID + e];
    float4 tq2 = tbl[src[2 * B + b] * HID + e];

#pragma unroll 4
    for (int t = 0; t < SEQ; ++t) {
        float4 tq3 = tbl[i3 * HID + e];
        i3 = src[((t + 4) & (SEQ - 1)) * B + b];

        // gate accumulators seeded with prescaled x-part; negated-prescaled dots
        float AI = tq0.x, AF = tq0.y, AG = tq0.z, AO = tq0.w;
#pragma unroll
        for (int m = 0; m < 20; ++m) {
            v2h hm = rdpair(hpk, 2 * m);
            AI = __builtin_amdgcn_fdot2(wi[m], hm, AI, false);
            AF = __builtin_amdgcn_fdot2(wf[m], hm, AF, false);
            AG = __builtin_amdgcn_fdot2(wg[m], hm, AG, false);
            AO = __builtin_amdgcn_fdot2(wo[m], hm, AO, false);
        }
        // acc already = -log2e*gate (or -2log2e for g): direct exp2 forms
        float si = frcp(1.f + fexp2(AI));
        float sf = frcp(1.f + fexp2(AF));
        float tg = fmaf(2.f, frcp(1.f + fexp2(AG)), -1.f);
        float so = frcp(1.f + fexp2(AO));

        c = fmaf(sf, c, si * tg);
        float th = fmaf(2.f, frcp(1.f + fexp2(-2.f * LOG2E * c)), -1.f);
        h = so * th;

        // repack h into f16 pairs (lanes 2p,2p+1 both hold (h[2p],h[2p+1]))
        float hp = __shfl_xor(h, 1);
        float lo = (lane & 1) ? hp : h;
        float hi = (lane & 1) ? h : hp;
        hpk = pkrtz(lo, hi);

        tq0 = tq1; tq1 = tq2; tq2 = tq3;
    }

    if (lane < HID) {
        est[b * 80 + lane]       = h;
        est[b * 80 + HID + lane] = c;
    }
}

// ---------------- kernel C: decoder, 40 steps, 1 chain per block (3 waves, fp32) ----------------
__global__ __launch_bounds__(192, 1) void dec_kernel(const float* __restrict__ dinp,
                                                     const float* __restrict__ Wih,
                                                     const float* __restrict__ Whh,
                                                     const float* __restrict__ bih,
                                                     const float* __restrict__ bhh,
                                                     const float* __restrict__ est,
                                                     float* __restrict__ out) {
    const int b    = blockIdx.x;
    const int tid  = threadIdx.x;
    const int lane = tid & 63;
    const int w    = tid >> 6;
    const int tt   = lane >> 4;
    const int q    = lane & 15;
    const int e    = 16 * w + q;
    const bool valid = (e < HID);
    const bool own   = valid && (tt == 0);
    const int j    = tt * HID + (valid ? e : 0);

    __shared__ __align__(16) float hbuf[2][48];

    float4 wi4[10], wh4[10];
#pragma unroll
    for (int r = 0; r < 10; ++r) {
        float4 ti = *reinterpret_cast<const float4*>(&Wih[j * HID + 4 * r]);
        float4 th = *reinterpret_cast<const float4*>(&Whh[j * HID + 4 * r]);
        if (!valid) { ti = make_float4(0,0,0,0); th = make_float4(0,0,0,0); }
        wi4[r] = ti; wh4[r] = th;
    }
    const float bj = valid ? (bih[j] + bhh[j]) : 0.f;

    const float mcoef = (tt == 2) ? (-2.f * LOG2E) : (-LOG2E);
    const float vsc   = (tt == 2) ? 2.f : 1.f;
    const float voff  = (tt == 2) ? -1.f : 0.f;

    float4 xr4[10], hr4[10];
#pragma unroll
    for (int r = 0; r < 10; ++r) {
        xr4[r] = *reinterpret_cast<const float4*>(&dinp[b * HID + 4 * r]);
        hr4[r] = *reinterpret_cast<const float4*>(&est[b * 80 + 4 * r]);
    }
    float c = valid ? est[b * 80 + HID + e] : 0.f;

    for (int t = 0; t < B; ++t) {
        float a0 = bj, a1 = 0.f, a2 = 0.f, a3 = 0.f;
#pragma unroll
        for (int r = 0; r < 10; ++r) {
            a0 = fmaf(wi4[r].x, xr4[r].x, a0);
            a1 = fmaf(wi4[r].y, xr4[r].y, a1);
            a2 = fmaf(wi4[r].z, xr4[r].z, a2);
            a3 = fmaf(wi4[r].w, xr4[r].w, a3);
            a0 = fmaf(wh4[r].x, hr4[r].x, a0);
            a1 = fmaf(wh4[r].y, hr4[r].y, a1);
            a2 = fmaf(wh4[r].z, hr4[r].z, a2);
            a3 = fmaf(wh4[r].w, hr4[r].w, a3);
        }
        float xg = (a0 + a1) + (a2 + a3);

        float E   = fexp2(mcoef * xg);
        float v   = frcp(1.f + E);
        float act = fmaf(vsc, v, voff);

        float ig = __shfl(act, q);
        float fg = __shfl(act, q + 16);
        float gg = __shfl(act, q + 32);
        float og = __shfl(act, q + 48);

        c = fmaf(fg, c, ig * gg);
        float Ec = fexp2(-2.f * LOG2E * c);
        float th = fmaf(2.f, frcp(1.f + Ec), -1.f);
        float h  = og * th;

        if (own) out[(t * B + b) * HID + e] = h;

        if (own) hbuf[t & 1][e] = h;
        __syncthreads();
#pragma unroll
        for (int r = 0; r < 10; ++r) {
            hr4[r] = *reinterpret_cast<const float4*>(&hbuf[t & 1][4 * r]);
            xr4[r] = hr4[r];   // next input is current output
        }
    }
}

extern "C" void kernel_launch(void* const* d_in, const int* in_sizes, int n_in,
                              void* d_out, int out_size, void* d_ws, size_t ws_size,
                              hipStream_t stream) {
    const int*   src  = (const int*)  d_in[0];
    const float* dinp = (const float*)d_in[1];
    const float* emb  = (const float*)d_in[2];
    const float* eWih = (const float*)d_in[3];
    const float* eWhh = (const float*)d_in[4];
    const float* ebih = (const float*)d_in[5];
    const float* ebhh = (const float*)d_in[6];
    const float* dWih = (const float*)d_in[7];
    const float* dWhh = (const float*)d_in[8];
    const float* dbih = (const float*)d_in[9];
    const float* dbhh = (const float*)d_in[10];
    float* out = (float*)d_out;

    float4* table4 = (float4*)d_ws;                       // 201*40 float4 (prescaled)
    float*  est    = (float*)(table4 + VOCAB * HID);      // 40*80 floats

    hipLaunchKernelGGL(setup_kernel, dim3(VOCAB), dim3(64), 0, stream, emb, eWih, ebih, ebhh, table4);
    hipLaunchKernelGGL(enc_kernel,   dim3(B),     dim3(64), 0, stream, src, eWhh, table4, est);
    hipLaunchKernelGGL(dec_kernel,   dim3(B),     dim3(192), 0, stream, dinp, dWih, dWhh, dbih, dbhh, est, out);
}

// Round 9
// 2313.585 us; speedup vs baseline: 1.1557x; 1.1057x over previous
//
#include <hip/hip_runtime.h>
#include <stdint.h>

#define SEQ 8192
#define B   40
#define EMBD 64
#define HID 40
#define VOCAB 201
#define LOG2E 1.4426950408889634f

typedef _Float16 v2h __attribute__((ext_vector_type(2)));
typedef float    v4f __attribute__((ext_vector_type(4)));

__device__ __forceinline__ float fexp2(float x) { float r; asm("v_exp_f32 %0, %1" : "=v"(r) : "v"(x)); return r; }
__device__ __forceinline__ float frcp (float x) { float r; asm("v_rcp_f32 %0, %1" : "=v"(r) : "v"(x)); return r; }
__device__ __forceinline__ float sigm (float x) { return frcp(1.f + fexp2(-LOG2E * x)); }
__device__ __forceinline__ float tanh_(float x) { return fmaf(2.f, frcp(1.f + fexp2(-2.f * LOG2E * x)), -1.f); }
__device__ __forceinline__ v2h rdpair(v2h v, int k) {
    int r = __builtin_amdgcn_readlane(__builtin_bit_cast(int, v), k);
    return __builtin_bit_cast(v2h, r);
}
__device__ __forceinline__ v2h pkrtz(float lo, float hi) {
    return __builtin_bit_cast(v2h, __builtin_amdgcn_cvt_pkrtz(lo, hi));
}

// ---------------- kernel A: table4[v][e] = (i,f,g,o) gate x-parts+bias (fp32) ----------------
__global__ void setup_kernel(const float* __restrict__ emb, const float* __restrict__ Wih,
                             const float* __restrict__ bih, const float* __restrict__ bhh,
                             float4* __restrict__ table4) {
    const int v = blockIdx.x;          // 0..200
    const int e = threadIdx.x;         // 0..63, active < 40
    if (e >= HID) return;
    const float* er = emb + v * EMBD;
    float acc[4];
#pragma unroll
    for (int g = 0; g < 4; ++g) {
        const int j = g * HID + e;
        const float* wr = Wih + j * EMBD;
        float a = bih[j] + bhh[j];
#pragma unroll 8
        for (int k = 0; k < EMBD; ++k) a = fmaf(er[k], wr[k], a);
        acc[g] = a;
    }
    table4[v * HID + e] = make_float4(acc[0], acc[1], acc[2], acc[3]);
}

// ---------------- kernel B: encoder — 1 wave/chain; asm loads + counted vmcnt(3) ----------------
__global__ __attribute__((amdgpu_flat_work_group_size(64, 64), amdgpu_waves_per_eu(1, 1)))
void enc_kernel(const int* __restrict__ src,
                const float* __restrict__ Whh,
                const float4* __restrict__ tbl,
                float* __restrict__ est) {
    const int b    = blockIdx.x;
    const int lane = threadIdx.x;
    const int e    = (lane < HID) ? lane : 0;   // clamp idle lanes

    __shared__ int ssrc[SEQ];
    for (int t = lane; t < SEQ; t += 64) ssrc[t] = src[t * B + b];

    // weights as f16 pairs (R4-proven numerics) -- 80 VGPRs
    v2h wi[20], wf[20], wg[20], wo[20];
#pragma unroll
    for (int r = 0; r < 10; ++r) {
        float4 ai = *reinterpret_cast<const float4*>(&Whh[(0 * HID + e) * HID + 4 * r]);
        float4 af = *reinterpret_cast<const float4*>(&Whh[(1 * HID + e) * HID + 4 * r]);
        float4 ag = *reinterpret_cast<const float4*>(&Whh[(2 * HID + e) * HID + 4 * r]);
        float4 ao = *reinterpret_cast<const float4*>(&Whh[(3 * HID + e) * HID + 4 * r]);
        wi[2*r]   = (v2h){(_Float16)ai.x, (_Float16)ai.y};
        wi[2*r+1] = (v2h){(_Float16)ai.z, (_Float16)ai.w};
        wf[2*r]   = (v2h){(_Float16)af.x, (_Float16)af.y};
        wf[2*r+1] = (v2h){(_Float16)af.z, (_Float16)af.w};
        wg[2*r]   = (v2h){(_Float16)ag.x, (_Float16)ag.y};
        wg[2*r+1] = (v2h){(_Float16)ag.z, (_Float16)ag.w};
        wo[2*r]   = (v2h){(_Float16)ao.x, (_Float16)ao.y};
        wo[2*r+1] = (v2h){(_Float16)ao.z, (_Float16)ao.w};
    }

    __syncthreads();   // ssrc staged

    // drain all prologue vm traffic so in-loop vmcnt counting is exact
    asm volatile("s_waitcnt vmcnt(0)" ::: "memory");

    const uint64_t base = (uint64_t)(const void*)tbl;
    v4f tq[4];
    int idxw[4];   // idx for step t+4 (slot t&3)
#pragma unroll
    for (int p = 0; p < 4; ++p) {
        uint64_t a = base + ((uint64_t)(uint32_t)(ssrc[p] * HID + e) << 4);
        asm volatile("global_load_dwordx4 %0, %1, off" : "=v"(tq[p]) : "v"(a));
        idxw[p] = ssrc[p + 4];
    }

    float c = 0.f, h = 0.f;
    v2h hpk = (v2h){(_Float16)0.f, (_Float16)0.f};

#pragma unroll 4
    for (int t = 0; t < SEQ; ++t) {
        const int s = t & 3;

        // wait only for the OLDEST load (t's); keep 3 in flight across iterations
        asm volatile("s_waitcnt vmcnt(3)");
        __builtin_amdgcn_sched_barrier(0);
        v4f q = tq[s];

        float AI = q.x, AF = q.y, AG = q.z, AO = q.w;
#pragma unroll
        for (int m = 0; m < 20; ++m) {
            v2h hm = rdpair(hpk, 2 * m);
            AI = __builtin_amdgcn_fdot2(wi[m], hm, AI, false);
            AF = __builtin_amdgcn_fdot2(wf[m], hm, AF, false);
            AG = __builtin_amdgcn_fdot2(wg[m], hm, AG, false);
            AO = __builtin_amdgcn_fdot2(wo[m], hm, AO, false);
        }
        float si = sigm(AI), sf = sigm(AF), tg = tanh_(AG), so = sigm(AO);
        c = fmaf(sf, c, si * tg);
        h = so * tanh_(c);

        // repack h into f16 pairs (lanes 2p,2p+1 both hold (h[2p],h[2p+1]))
        float hp = __shfl_xor(h, 1);
        float lo = (lane & 1) ? hp : h;
        float hi = (lane & 1) ? h : hp;
        hpk = pkrtz(lo, hi);

        // issue load for step t+4 into the slot just consumed
        uint64_t a = base + ((uint64_t)(uint32_t)(idxw[s] * HID + e) << 4);
        asm volatile("global_load_dwordx4 %0, %1, off" : "=v"(tq[s]) : "v"(a));
        // refill idx window (for step t+8) from LDS — consumed 4 iters later
        idxw[s] = ssrc[(t + 8) & (SEQ - 1)];
    }

    if (lane < HID) {
        est[b * 80 + lane]       = h;
        est[b * 80 + HID + lane] = c;
    }
}

// ---------------- kernel C: decoder, 40 steps, 1 chain per block (3 waves, fp32) ----------------
__global__ __launch_bounds__(192, 1) void dec_kernel(const float* __restrict__ dinp,
                                                     const float* __restrict__ Wih,
                                                     const float* __restrict__ Whh,
                                                     const float* __restrict__ bih,
                                                     const float* __restrict__ bhh,
                                                     const float* __restrict__ est,
                                                     float* __restrict__ out) {
    const int b    = blockIdx.x;
    const int tid  = threadIdx.x;
    const int lane = tid & 63;
    const int w    = tid >> 6;
    const int tt   = lane >> 4;
    const int q    = lane & 15;
    const int e    = 16 * w + q;
    const bool valid = (e < HID);
    const bool own   = valid && (tt == 0);
    const int j    = tt * HID + (valid ? e : 0);

    __shared__ __align__(16) float hbuf[2][48];

    float4 wi4[10], wh4[10];
#pragma unroll
    for (int r = 0; r < 10; ++r) {
        float4 ti = *reinterpret_cast<const float4*>(&Wih[j * HID + 4 * r]);
        float4 th = *reinterpret_cast<const float4*>(&Whh[j * HID + 4 * r]);
        if (!valid) { ti = make_float4(0,0,0,0); th = make_float4(0,0,0,0); }
        wi4[r] = ti; wh4[r] = th;
    }
    const float bj = valid ? (bih[j] + bhh[j]) : 0.f;

    const float mcoef = (tt == 2) ? (-2.f * LOG2E) : (-LOG2E);
    const float vsc   = (tt == 2) ? 2.f : 1.f;
    const float voff  = (tt == 2) ? -1.f : 0.f;

    float4 xr4[10], hr4[10];
#pragma unroll
    for (int r = 0; r < 10; ++r) {
        xr4[r] = *reinterpret_cast<const float4*>(&dinp[b * HID + 4 * r]);
        hr4[r] = *reinterpret_cast<const float4*>(&est[b * 80 + 4 * r]);
    }
    float c = valid ? est[b * 80 + HID + e] : 0.f;

    for (int t = 0; t < B; ++t) {
        float a0 = bj, a1 = 0.f, a2 = 0.f, a3 = 0.f;
#pragma unroll
        for (int r = 0; r < 10; ++r) {
            a0 = fmaf(wi4[r].x, xr4[r].x, a0);
            a1 = fmaf(wi4[r].y, xr4[r].y, a1);
            a2 = fmaf(wi4[r].z, xr4[r].z, a2);
            a3 = fmaf(wi4[r].w, xr4[r].w, a3);
            a0 = fmaf(wh4[r].x, hr4[r].x, a0);
            a1 = fmaf(wh4[r].y, hr4[r].y, a1);
            a2 = fmaf(wh4[r].z, hr4[r].z, a2);
            a3 = fmaf(wh4[r].w, hr4[r].w, a3);
        }
        float xg = (a0 + a1) + (a2 + a3);

        float E   = fexp2(mcoef * xg);
        float v   = frcp(1.f + E);
        float act = fmaf(vsc, v, voff);

        float ig = __shfl(act, q);
        float fg = __shfl(act, q + 16);
        float gg = __shfl(act, q + 32);
        float og = __shfl(act, q + 48);

        c = fmaf(fg, c, ig * gg);
        float Ec = fexp2(-2.f * LOG2E * c);
        float th = fmaf(2.f, frcp(1.f + Ec), -1.f);
        float h  = og * th;

        if (own) out[(t * B + b) * HID + e] = h;

        if (own) hbuf[t & 1][e] = h;
        __syncthreads();
#pragma unroll
        for (int r = 0; r < 10; ++r) {
            hr4[r] = *reinterpret_cast<const float4*>(&hbuf[t & 1][4 * r]);
            xr4[r] = hr4[r];   // next input is current output
        }
    }
}

extern "C" void kernel_launch(void* const* d_in, const int* in_sizes, int n_in,
                              void* d_out, int out_size, void* d_ws, size_t ws_size,
                              hipStream_t stream) {
    const int*   src  = (const int*)  d_in[0];
    const float* dinp = (const float*)d_in[1];
    const float* emb  = (const float*)d_in[2];
    const float* eWih = (const float*)d_in[3];
    const float* eWhh = (const float*)d_in[4];
    const float* ebih = (const float*)d_in[5];
    const float* ebhh = (const float*)d_in[6];
    const float* dWih = (const float*)d_in[7];
    const float* dWhh = (const float*)d_in[8];
    const float* dbih = (const float*)d_in[9];
    const float* dbhh = (const float*)d_in[10];
    float* out = (float*)d_out;

    float4* table4 = (float4*)d_ws;                       // 201*40 float4
    float*  est    = (float*)(table4 + VOCAB * HID);      // 40*80 floats

    hipLaunchKernelGGL(setup_kernel, dim3(VOCAB), dim3(64), 0, stream, emb, eWih, ebih, ebhh, table4);
    hipLaunchKernelGGL(enc_kernel,   dim3(B),     dim3(64), 0, stream, src, eWhh, table4, est);
    hipLaunchKernelGGL(dec_kernel,   dim3(B),     dim3(192), 0, stream, dinp, dWih, dWhh, dbih, dbhh, est, out);
}

// Round 11
// 2262.435 us; speedup vs baseline: 1.1819x; 1.0226x over previous
//
#include <hip/hip_runtime.h>
#include <stdint.h>

#define SEQ 8192
#define B   40
#define EMBD 64
#define HID 40
#define VOCAB 201
#define LOG2E 1.4426950408889634f

typedef _Float16 v2h __attribute__((ext_vector_type(2)));
typedef float    v4f __attribute__((ext_vector_type(4)));

__device__ __forceinline__ float fexp2(float x) { float r; asm("v_exp_f32 %0, %1" : "=v"(r) : "v"(x)); return r; }
__device__ __forceinline__ float frcp (float x) { float r; asm("v_rcp_f32 %0, %1" : "=v"(r) : "v"(x)); return r; }
__device__ __forceinline__ float sigm (float x) { return frcp(1.f + fexp2(-LOG2E * x)); }
__device__ __forceinline__ float tanh_(float x) { return fmaf(2.f, frcp(1.f + fexp2(-2.f * LOG2E * x)), -1.f); }
__device__ __forceinline__ v2h rdpair(v2h v, int k) {
    int r = __builtin_amdgcn_readlane(__builtin_bit_cast(int, v), k);
    return __builtin_bit_cast(v2h, r);
}
__device__ __forceinline__ v2h pkrtz(float lo, float hi) {
    return __builtin_bit_cast(v2h, __builtin_amdgcn_cvt_pkrtz(lo, hi));
}
// DPP quad_perm broadcast (pure VALU, 1 instr); CTRL must be an immediate
template <int CTRL>
__device__ __forceinline__ float dppq(float v) {
    return __builtin_bit_cast(float,
        __builtin_amdgcn_update_dpp(0, __builtin_bit_cast(int, v), CTRL, 0xF, 0xF, true));
}

// ---------------- kernel A: table4[v][e] = (i,f,g,o) gate x-parts+bias (fp32) ----------------
__global__ void setup_kernel(const float* __restrict__ emb, const float* __restrict__ Wih,
                             const float* __restrict__ bih, const float* __restrict__ bhh,
                             float4* __restrict__ table4) {
    const int v = blockIdx.x;          // 0..200
    const int e = threadIdx.x;         // 0..63, active < 40
    if (e >= HID) return;
    const float* er = emb + v * EMBD;
    float acc[4];
#pragma unroll
    for (int g = 0; g < 4; ++g) {
        const int j = g * HID + e;
        const float* wr = Wih + j * EMBD;
        float a = bih[j] + bhh[j];
#pragma unroll 8
        for (int k = 0; k < EMBD; ++k) a = fmaf(er[k], wr[k], a);
        acc[g] = a;
    }
    table4[v * HID + e] = make_float4(acc[0], acc[1], acc[2], acc[3]);
}

// ---------------- kernel B: encoder — 1 wave/chain; asm loads + vmcnt(3); DPP repack ----------------
__global__ __attribute__((amdgpu_flat_work_group_size(64, 64), amdgpu_waves_per_eu(1, 1)))
void enc_kernel(const int* __restrict__ src,
                const float* __restrict__ Whh,
                const float4* __restrict__ tbl,
                float* __restrict__ est) {
    const int b    = blockIdx.x;
    const int lane = threadIdx.x;
    const int e    = (lane < HID) ? lane : 0;   // clamp idle lanes

    __shared__ int ssrc[SEQ];
    for (int t = lane; t < SEQ; t += 64) ssrc[t] = src[t * B + b];

    // weights as f16 pairs -- 80 VGPRs
    v2h wi[20], wf[20], wg[20], wo[20];
#pragma unroll
    for (int r = 0; r < 10; ++r) {
        float4 ai = *reinterpret_cast<const float4*>(&Whh[(0 * HID + e) * HID + 4 * r]);
        float4 af = *reinterpret_cast<const float4*>(&Whh[(1 * HID + e) * HID + 4 * r]);
        float4 ag = *reinterpret_cast<const float4*>(&Whh[(2 * HID + e) * HID + 4 * r]);
        float4 ao = *reinterpret_cast<const float4*>(&Whh[(3 * HID + e) * HID + 4 * r]);
        wi[2*r]   = (v2h){(_Float16)ai.x, (_Float16)ai.y};
        wi[2*r+1] = (v2h){(_Float16)ai.z, (_Float16)ai.w};
        wf[2*r]   = (v2h){(_Float16)af.x, (_Float16)af.y};
        wf[2*r+1] = (v2h){(_Float16)af.z, (_Float16)af.w};
        wg[2*r]   = (v2h){(_Float16)ag.x, (_Float16)ag.y};
        wg[2*r+1] = (v2h){(_Float16)ag.z, (_Float16)ag.w};
        wo[2*r]   = (v2h){(_Float16)ao.x, (_Float16)ao.y};
        wo[2*r+1] = (v2h){(_Float16)ao.z, (_Float16)ao.w};
    }

    __syncthreads();   // ssrc staged

    asm volatile("s_waitcnt vmcnt(0)" ::: "memory");

    const uint64_t base = (uint64_t)(const void*)tbl;
    v4f tq[4];
    int idxw[4];   // idx for step t+4 (slot t&3)
#pragma unroll
    for (int p = 0; p < 4; ++p) {
        uint64_t a = base + ((uint64_t)(uint32_t)(ssrc[p] * HID + e) << 4);
        asm volatile("global_load_dwordx4 %0, %1, off" : "=v"(tq[p]) : "v"(a));
        idxw[p] = ssrc[p + 4];
    }

    float c = 0.f, h = 0.f;
    v2h hpk = (v2h){(_Float16)0.f, (_Float16)0.f};

#pragma unroll 4
    for (int t = 0; t < SEQ; ++t) {
        const int s = t & 3;

        asm volatile("s_waitcnt vmcnt(3)");
        __builtin_amdgcn_sched_barrier(0);
        v4f q = tq[s];

        float AI = q.x, AF = q.y, AG = q.z, AO = q.w;
#pragma unroll
        for (int m = 0; m < 20; ++m) {
            v2h hm = rdpair(hpk, 2 * m);
            AI = __builtin_amdgcn_fdot2(wi[m], hm, AI, false);
            AF = __builtin_amdgcn_fdot2(wf[m], hm, AF, false);
            AG = __builtin_amdgcn_fdot2(wg[m], hm, AG, false);
            AO = __builtin_amdgcn_fdot2(wo[m], hm, AO, false);
        }
        float si = sigm(AI), sf = sigm(AF), tg = tanh_(AG), so = sigm(AO);
        c = fmaf(sf, c, si * tg);
        h = so * tanh_(c);

        // repack h into f16 pairs via DPP quad_perm (no LDS, no shfl)
        float hA = dppq<0xA0>(h);   // quad_perm [0,0,2,2] -> even member of pair
        float hB = dppq<0xF5>(h);   // quad_perm [1,1,3,3] -> odd member of pair
        hpk = pkrtz(hA, hB);

        // issue load for step t+4 into the slot just consumed
        uint64_t a = base + ((uint64_t)(uint32_t)(idxw[s] * HID + e) << 4);
        asm volatile("global_load_dwordx4 %0, %1, off" : "=v"(tq[s]) : "v"(a));
        idxw[s] = ssrc[(t + 8) & (SEQ - 1)];
    }

    if (lane < HID) {
        est[b * 80 + lane]       = h;
        est[b * 80 + HID + lane] = c;
    }
}

// ---------------- kernel C: decoder, 40 steps, 1 chain per block (3 waves, fp32) ----------------
__global__ __launch_bounds__(192, 1) void dec_kernel(const float* __restrict__ dinp,
                                                     const float* __restrict__ Wih,
                                                     const float* __restrict__ Whh,
                                                     const float* __restrict__ bih,
                                                     const float* __restrict__ bhh,
                                                     const float* __restrict__ est,
                                                     float* __restrict__ out) {
    const int b    = blockIdx.x;
    const int tid  = threadIdx.x;
    const int lane = tid & 63;
    const int w    = tid >> 6;
    const int tt   = lane >> 4;
    const int q    = lane & 15;
    const int e    = 16 * w + q;
    const bool valid = (e < HID);
    const bool own   = valid && (tt == 0);
    const int j    = tt * HID + (valid ? e : 0);

    __shared__ __align__(16) float hbuf[2][48];

    float4 wi4[10], wh4[10];
#pragma unroll
    for (int r = 0; r < 10; ++r) {
        float4 ti = *reinterpret_cast<const float4*>(&Wih[j * HID + 4 * r]);
        float4 th = *reinterpret_cast<const float4*>(&Whh[j * HID + 4 * r]);
        if (!valid) { ti = make_float4(0,0,0,0); th = make_float4(0,0,0,0); }
        wi4[r] = ti; wh4[r] = th;
    }
    const float bj = valid ? (bih[j] + bhh[j]) : 0.f;

    const float mcoef = (tt == 2) ? (-2.f * LOG2E) : (-LOG2E);
    const float vsc   = (tt == 2) ? 2.f : 1.f;
    const float voff  = (tt == 2) ? -1.f : 0.f;

    float4 xr4[10], hr4[10];
#pragma unroll
    for (int r = 0; r < 10; ++r) {
        xr4[r] = *reinterpret_cast<const float4*>(&dinp[b * HID + 4 * r]);
        hr4[r] = *reinterpret_cast<const float4*>(&est[b * 80 + 4 * r]);
    }
    float c = valid ? est[b * 80 + HID + e] : 0.f;

    for (int t = 0; t < B; ++t) {
        float a0 = bj, a1 = 0.f, a2 = 0.f, a3 = 0.f;
#pragma unroll
        for (int r = 0; r < 10; ++r) {
            a0 = fmaf(wi4[r].x, xr4[r].x, a0);
            a1 = fmaf(wi4[r].y, xr4[r].y, a1);
            a2 = fmaf(wi4[r].z, xr4[r].z, a2);
            a3 = fmaf(wi4[r].w, xr4[r].w, a3);
            a0 = fmaf(wh4[r].x, hr4[r].x, a0);
            a1 = fmaf(wh4[r].y, hr4[r].y, a1);
            a2 = fmaf(wh4[r].z, hr4[r].z, a2);
            a3 = fmaf(wh4[r].w, hr4[r].w, a3);
        }
        float xg = (a0 + a1) + (a2 + a3);

        float E   = fexp2(mcoef * xg);
        float v   = frcp(1.f + E);
        float act = fmaf(vsc, v, voff);

        float ig = __shfl(act, q);
        float fg = __shfl(act, q + 16);
        float gg = __shfl(act, q + 32);
        float og = __shfl(act, q + 48);

        c = fmaf(fg, c, ig * gg);
        float Ec = fexp2(-2.f * LOG2E * c);
        float th = fmaf(2.f, frcp(1.f + Ec), -1.f);
        float h  = og * th;

        if (own) out[(t * B + b) * HID + e] = h;

        if (own) hbuf[t & 1][e] = h;
        __syncthreads();
#pragma unroll
        for (int r = 0; r < 10; ++r) {
            hr4[r] = *reinterpret_cast<const float4*>(&hbuf[t & 1][4 * r]);
            xr4[r] = hr4[r];   // next input is current output
        }
    }
}

extern "C" void kernel_launch(void* const* d_in, const int* in_sizes, int n_in,
                              void* d_out, int out_size, void* d_ws, size_t ws_size,
                              hipStream_t stream) {
    const int*   src  = (const int*)  d_in[0];
    const float* dinp = (const float*)d_in[1];
    const float* emb  = (const float*)d_in[2];
    const float* eWih = (const float*)d_in[3];
    const float* eWhh = (const float*)d_in[4];
    const float* ebih = (const float*)d_in[5];
    const float* ebhh = (const float*)d_in[6];
    const float* dWih = (const float*)d_in[7];
    const float* dWhh = (const float*)d_in[8];
    const float* dbih = (const float*)d_in[9];
    const float* dbhh = (const float*)d_in[10];
    float* out = (float*)d_out;

    float4* table4 = (float4*)d_ws;                       // 201*40 float4
    float*  est    = (float*)(table4 + VOCAB * HID);      // 40*80 floats

    hipLaunchKernelGGL(setup_kernel, dim3(VOCAB), dim3(64), 0, stream, emb, eWih, ebih, ebhh, table4);
    hipLaunchKernelGGL(enc_kernel,   dim3(B),     dim3(64), 0, stream, src, eWhh, table4, est);
    hipLaunchKernelGGL(dec_kernel,   dim3(B),     dim3(192), 0, stream, dinp, dWih, dWhh, dbih, dbhh, est, out);
}